// Round 5
// baseline (379.310 us; speedup 1.0000x reference)
//
#include <hip/hip_runtime.h>

typedef unsigned short u16;
typedef unsigned int u32;
typedef __bf16 bf16x8 __attribute__((ext_vector_type(8)));
typedef float f32x4 __attribute__((ext_vector_type(4)));
typedef float f32x16 __attribute__((ext_vector_type(16)));

#define B_ 16
#define C_ 512
#define N_ 1024
#define NB_ 16384   // B_*N_
#define K_ 512
#define M3_ 1536
#define SCALE_Q 0.18033688011112042f  // 0.125 * log2(e)

// ---- helpers ----
__device__ __forceinline__ u16 f2bf(float f) {
  u32 u = __float_as_uint(f);
  u32 r = (u + 0x7FFFu + ((u >> 16) & 1u)) >> 16;  // RNE
  return (u16)r;
}

__device__ __forceinline__ void gl_lds16(const void* g, void* l) {
  __builtin_amdgcn_global_load_lds(
      (const __attribute__((address_space(1))) u32*)(uintptr_t)g,
      (__attribute__((address_space(3))) u32*)(u32)(uintptr_t)l, 16, 0, 0);
}

__device__ __forceinline__ u32 cvtpk(float lo, float hi) {
  u32 r;
  asm("v_cvt_pk_bf16_f32 %0, %1, %2" : "=v"(r) : "v"(lo), "v"(hi));
  return r;
}

__device__ __forceinline__ float exp2a(float x) {
  float r;
  asm("v_exp_f32 %0, %1" : "=v"(r) : "v"(x));
  return r;
}

// (a,b) -> a' = {a_lo, b_lo}, b' = {a_hi, b_hi}
__device__ __forceinline__ void plswap2(u32& a, u32& b) {
#if __has_builtin(__builtin_amdgcn_permlane32_swap)
  auto r = __builtin_amdgcn_permlane32_swap((int)a, (int)b, false, false);
  a = (u32)r[0];
  b = (u32)r[1];
#else
  asm("v_permlane32_swap_b32 %0, %1" : "+v"(a), "+v"(b));
#endif
}

__device__ __forceinline__ float xhalf_sum(float x) {
  u32 a = __float_as_uint(x), b = a;
  plswap2(a, b);
  return __uint_as_float(a) + __uint_as_float(b);
}

// ---- kernel 1: fp32 -> bf16 cast for weights ----
__global__ __launch_bounds__(256) void cast_bf16_kernel(const float* __restrict__ src,
                                                        u16* __restrict__ dst, int n) {
  int i = blockIdx.x * 256 + threadIdx.x;
  if (i < n) dst[i] = f2bf(src[i]);
}

// ---- kernel 2: GroupNorm, writes h^T as (B*N, C) bf16 ----
__global__ __launch_bounds__(256) void gnorm_kernel(const float* __restrict__ x,
                                                    const float* __restrict__ gamma,
                                                    const float* __restrict__ beta,
                                                    u16* __restrict__ ht) {
  int blk = blockIdx.x;
  int b = blk >> 5, g = blk & 31;
  int t = threadIdx.x;
  const float* xb = x + ((size_t)(b * C_ + g * 16) << 10);
  float v[16][4];
  float s = 0.f, sq = 0.f;
#pragma unroll
  for (int cc = 0; cc < 16; ++cc) {
#pragma unroll
    for (int r = 0; r < 4; ++r) {
      float f = xb[cc * 1024 + r * 256 + t];
      v[cc][r] = f; s += f; sq += f * f;
    }
  }
#pragma unroll
  for (int m = 32; m >= 1; m >>= 1) { s += __shfl_xor(s, m, 64); sq += __shfl_xor(sq, m, 64); }
  __shared__ float red[8];
  int w = t >> 6;
  if ((t & 63) == 0) { red[w * 2] = s; red[w * 2 + 1] = sq; }
  __syncthreads();
  s = red[0] + red[2] + red[4] + red[6];
  sq = red[1] + red[3] + red[5] + red[7];
  float mean = s * (1.f / 16384.f);
  float var = sq * (1.f / 16384.f) - mean * mean;
  float rstd = rsqrtf(var + 1e-5f);
  float gm[16], bt[16];
#pragma unroll
  for (int cc = 0; cc < 16; ++cc) {
    gm[cc] = gamma[g * 16 + cc] * rstd;
    bt[cc] = beta[g * 16 + cc];
  }
  u16* hb = ht + ((size_t)(b << 10)) * C_ + g * 16;
#pragma unroll
  for (int r = 0; r < 4; ++r) {
    u32 pk[8];
#pragma unroll
    for (int q = 0; q < 8; ++q) {
      float f0 = (v[2 * q][r] - mean) * gm[2 * q] + bt[2 * q];
      float f1 = (v[2 * q + 1][r] - mean) * gm[2 * q + 1] + bt[2 * q + 1];
      pk[q] = (u32)f2bf(f0) | ((u32)f2bf(f1) << 16);
    }
    u16* dp = hb + (size_t)(r * 256 + t) * C_;
    uint4 a = {pk[0], pk[1], pk[2], pk[3]};
    uint4 b4 = {pk[4], pk[5], pk[6], pk[7]};
    *(uint4*)dp = a;
    *(uint4*)(dp + 8) = b4;
  }
}

// ---- GEMM: C[MxNB] = A[MxK] * BT[NBxK]^T ; 128x128 tile, BK=64, 4 waves ----
// EPI 0: qkv GEMM. q,k bands (rows<1024) are stored TRANSPOSED per-(b,h) as
//        (n, d) bf16 into qTo/kTo (q pre-scaled); v band stored (o, bn) in Co.
// EPI 1: out = x + val + bias -> fp32 (b,c,n)
template <int EPI>
__global__ __launch_bounds__(256) void gemm_kernel(const u16* __restrict__ A,
                                                   const u16* __restrict__ BT,
                                                   const float* __restrict__ bias,
                                                   u16* __restrict__ Co,
                                                   u16* __restrict__ qTo,
                                                   u16* __restrict__ kTo,
                                                   const float* __restrict__ xres,
                                                   float* __restrict__ Fo) {
  __shared__ u16 ldsA[128 * 64];
  __shared__ u16 ldsB[128 * 64];
  int t = threadIdx.x;
  int l = t & 63, w = t >> 6;
  int wr = w >> 1, wc = w & 1;
  int ro0 = blockIdx.y * 128, co0 = blockIdx.x * 128;
  f32x4 acc[4][4];
#pragma unroll
  for (int m = 0; m < 4; ++m)
#pragma unroll
    for (int n = 0; n < 4; ++n) acc[m][n] = {0.f, 0.f, 0.f, 0.f};
  int srow = t >> 3, sg = t & 7;
  for (int kt = 0; kt < 8; ++kt) {
    int k0 = kt * 64;
#pragma unroll
    for (int i = 0; i < 4; ++i) {
      int row = i * 32 + srow;
      int gl = sg ^ (row & 7);
      gl_lds16(A + (size_t)(ro0 + row) * K_ + k0 + gl * 8, ldsA + (i * 32 + w * 8) * 64);
      gl_lds16(BT + (size_t)(co0 + row) * K_ + k0 + gl * 8, ldsB + (i * 32 + w * 8) * 64);
    }
    __syncthreads();
#pragma unroll
    for (int ks = 0; ks < 2; ++ks) {
      bf16x8 af[4], bfr[4];
#pragma unroll
      for (int m = 0; m < 4; ++m) {
        int row = wr * 64 + m * 16 + (l & 15);
        int ph = (ks * 4 + (l >> 4)) ^ (row & 7);
        af[m] = *(const bf16x8*)&ldsA[row * 64 + ph * 8];
      }
#pragma unroll
      for (int n = 0; n < 4; ++n) {
        int row = wc * 64 + n * 16 + (l & 15);
        int ph = (ks * 4 + (l >> 4)) ^ (row & 7);
        bfr[n] = *(const bf16x8*)&ldsB[row * 64 + ph * 8];
      }
#pragma unroll
      for (int m = 0; m < 4; ++m)
#pragma unroll
        for (int n = 0; n < 4; ++n)
          acc[m][n] = __builtin_amdgcn_mfma_f32_16x16x32_bf16(af[m], bfr[n], acc[m][n], 0, 0, 0);
    }
    __syncthreads();
  }
  if (EPI == 0 && ro0 < 1024) {
    // q/k band: transposed store into (b,h)(n,d) layout
    int sel = ro0 >> 9;
    u16* dstb = sel ? kTo : qTo;
    float scl = sel ? 1.f : SCALE_Q;
#pragma unroll
    for (int m = 0; m < 4; ++m) {
      int row0 = ro0 + wr * 64 + m * 16 + (l >> 4) * 4;
      int o = row0 & 511;
      int h = o >> 6, d0 = o & 63;
      float bv0 = bias[row0], bv1 = bias[row0 + 1];
      float bv2 = bias[row0 + 2], bv3 = bias[row0 + 3];
#pragma unroll
      for (int n = 0; n < 4; ++n) {
        int col = co0 + wc * 64 + n * 16 + (l & 15);
        int bb = col >> 10, nn = col & 1023;
        float v0 = (acc[m][n][0] + bv0) * scl;
        float v1 = (acc[m][n][1] + bv1) * scl;
        float v2 = (acc[m][n][2] + bv2) * scl;
        float v3 = (acc[m][n][3] + bv3) * scl;
        uint2 ov = {cvtpk(v0, v1), cvtpk(v2, v3)};
        *(uint2*)(dstb + ((size_t)((bb * 8 + h) << 10) + nn) * 64 + d0) = ov;
      }
    }
  } else {
#pragma unroll
    for (int m = 0; m < 4; ++m) {
#pragma unroll
      for (int j = 0; j < 4; ++j) {
        int row = ro0 + wr * 64 + m * 16 + (l >> 4) * 4 + j;
        float bv = bias[row];
#pragma unroll
        for (int n = 0; n < 4; ++n) {
          int col = co0 + wc * 64 + n * 16 + (l & 15);
          float val = acc[m][n][j] + bv;
          if (EPI == 0) {
            Co[(size_t)row * NB_ + col] = f2bf(val);
          } else {
            int bb = col >> 10, nn = col & 1023;
            size_t oi = (((size_t)(bb * C_ + row)) << 10) + nn;
            Fo[oi] = xres[oi] + val;
          }
        }
      }
    }
  }
}

// ---- kernel 4: flash attention, 4 waves = 2 q-halves x 2 kv-halves ----
// Each wave: 64 q-rows, 16 KV-tiles (KVBLK=32). The wk-pair shares one
// double-buffered K+V LDS stream (staging split: wq=0 stages K, wq=1 stages V).
// Per step: vmcnt(0) on 1-step-old prefetch + one raw s_barrier; prefetch of
// tile s+1 is issued AFTER barrier(s) so buffer writes can't race readers.
// kv-partials merge at the end (no online max -> plain adds).
__global__ __launch_bounds__(256, 4) void attn_kernel(const u16* __restrict__ qT,
                                                      const u16* __restrict__ kT,
                                                      const u16* __restrict__ qkv,
                                                      u16* __restrict__ aoT) {
  __shared__ u16 KV[2][2][4096];   // [wk][buf][0..2047 = K(32kv x 64d) | 2048..4095 = V(64d x 32kv)]
  __shared__ float smL[2][2][64];  // [wq][qg][lane]
  int bid = blockIdx.x;
  int wid = (bid & 7) * 128 + (bid >> 3);  // XCD swizzle (1024 blocks, 8 XCDs)
  int qt2 = wid & 7, h = (wid >> 3) & 7, b = wid >> 6;
  int bh = b * 8 + h;
  int t = threadIdx.x, l = t & 63, w = t >> 6;
  int wq = w >> 1, wk = w & 1;
  int lq = l & 31, hi = l >> 5;
  int q0 = qt2 * 128 + wq * 64;

  // Q fragments (scale pre-folded in qkv GEMM epilogue)
  bf16x8 qf[2][4];
#pragma unroll
  for (int qg = 0; qg < 2; ++qg) {
    const u16* qbase = qT + ((size_t)(bh << 10) + q0 + qg * 32 + lq) * 64 + hi * 8;
#pragma unroll
    for (int kc = 0; kc < 4; ++kc) qf[qg][kc] = *(const bf16x8*)(qbase + kc * 16);
  }

  f32x16 accO[2][2];
#pragma unroll
  for (int qg = 0; qg < 2; ++qg)
#pragma unroll
    for (int dt = 0; dt < 2; ++dt)
#pragma unroll
      for (int r = 0; r < 16; ++r) accO[qg][dt][r] = 0.f;
  float lsum[2] = {0.f, 0.f};

  // staging source pointers: this wave stages K (wq=0) or V (wq=1) of kv-half wk
  const u16* k_src = kT + ((size_t)(bh << 10) + wk * 512 + (l >> 3)) * 64 +
                     (((l & 7) ^ ((l >> 3) & 7)) * 8);
  const u16* v_src = qkv + (size_t)(2 * C_ + h * 64 + (l >> 2)) * NB_ + (b << 10) + wk * 512 +
                     (((l & 3) ^ ((l >> 3) & 3)) * 8);

  u16* kvbase = &KV[wk][0][0];  // buf stride = 4096 elems

  // LDS read pointers (within buf 0)
  const u16* kfp[4];
#pragma unroll
  for (int kc = 0; kc < 4; ++kc)
    kfp[kc] = kvbase + lq * 64 + (((2 * kc + hi) ^ (lq & 7)) * 8);
  const u16* vfp[4];
#pragma unroll
  for (int dt = 0; dt < 2; ++dt)
#pragma unroll
    for (int kcc = 0; kcc < 2; ++kcc)
      vfp[dt * 2 + kcc] = kvbase + 2048 + (dt * 32 + lq) * 32 + (((kcc * 2 + hi) ^ ((lq >> 1) & 3)) * 8);

  auto stage = [&](int buf) {
    u16* dst = kvbase + buf * 4096 + (wq ? 2048 : 0);
    if (wq == 0) {
#pragma unroll
      for (int i = 0; i < 4; ++i) gl_lds16(k_src + i * 512, dst + i * 512);
      k_src += 2048;  // 32 kv-rows
    } else {
#pragma unroll
      for (int i = 0; i < 4; ++i) gl_lds16(v_src + (size_t)i * 16 * NB_, dst + i * 512);
      v_src += 32;    // 32 kv-cols
    }
  };

  auto step = [&](int buf, bool dostage) {
    asm volatile("s_waitcnt vmcnt(0)" ::: "memory");  // own half of tile s (prefetched a step ago)
    __builtin_amdgcn_sched_barrier(0);
    __builtin_amdgcn_s_barrier();                     // partner's half retired too
    __builtin_amdgcn_sched_barrier(0);
    if (dostage) stage(buf ^ 1);                      // prefetch tile s+1 (post-barrier: no race)
    bf16x8 kf[4], vf[4];
#pragma unroll
    for (int kc = 0; kc < 4; ++kc) kf[kc] = *(const bf16x8*)(kfp[kc] + buf * 4096);
#pragma unroll
    for (int j = 0; j < 4; ++j) vf[j] = *(const bf16x8*)(vfp[j] + buf * 4096);
    f32x16 sc[2];
#pragma unroll
    for (int qg = 0; qg < 2; ++qg)
#pragma unroll
      for (int r = 0; r < 16; ++r) sc[qg][r] = 0.f;
    __builtin_amdgcn_s_setprio(1);
#pragma unroll
    for (int kc = 0; kc < 4; ++kc) {
      sc[0] = __builtin_amdgcn_mfma_f32_32x32x16_bf16(kf[kc], qf[0][kc], sc[0], 0, 0, 0);
      sc[1] = __builtin_amdgcn_mfma_f32_32x32x16_bf16(kf[kc], qf[1][kc], sc[1], 0, 0, 0);
    }
    __builtin_amdgcn_s_setprio(0);
    u32 pfu[2][2][4];
#pragma unroll
    for (int qg = 0; qg < 2; ++qg) {
      float p0 = 0.f, p1 = 0.f, p2 = 0.f, p3 = 0.f;
#pragma unroll
      for (int r = 0; r < 4; ++r) {
        float e0 = exp2a(sc[qg][4 * r + 0]);
        float e1 = exp2a(sc[qg][4 * r + 1]);
        float e2 = exp2a(sc[qg][4 * r + 2]);
        float e3 = exp2a(sc[qg][4 * r + 3]);
        sc[qg][4 * r + 0] = e0; sc[qg][4 * r + 1] = e1;
        sc[qg][4 * r + 2] = e2; sc[qg][4 * r + 3] = e3;
        p0 += e0; p1 += e1; p2 += e2; p3 += e3;
      }
      lsum[qg] += (p0 + p1) + (p2 + p3);
      u32 pk[8];
#pragma unroll
      for (int p = 0; p < 8; ++p) pk[p] = cvtpk(sc[qg][2 * p], sc[qg][2 * p + 1]);
#pragma unroll
      for (int cc = 0; cc < 2; ++cc) {
        u32 w0 = pk[cc * 4 + 0], w2 = pk[cc * 4 + 2];
        u32 w1 = pk[cc * 4 + 1], w3 = pk[cc * 4 + 3];
        plswap2(w0, w2);
        plswap2(w1, w3);
        pfu[qg][cc][0] = w0; pfu[qg][cc][1] = w1;
        pfu[qg][cc][2] = w2; pfu[qg][cc][3] = w3;
      }
    }
    __builtin_amdgcn_s_setprio(1);
#pragma unroll
    for (int kcc = 0; kcc < 2; ++kcc)
#pragma unroll
      for (int dt = 0; dt < 2; ++dt) {
        bf16x8 vv = vf[dt * 2 + kcc];
#pragma unroll
        for (int qg = 0; qg < 2; ++qg) {
          union { u32 u[4]; bf16x8 v; } pf;
          pf.u[0] = pfu[qg][kcc][0]; pf.u[1] = pfu[qg][kcc][1];
          pf.u[2] = pfu[qg][kcc][2]; pf.u[3] = pfu[qg][kcc][3];
          accO[qg][dt] = __builtin_amdgcn_mfma_f32_32x32x16_bf16(vv, pf.v, accO[qg][dt], 0, 0, 0);
        }
      }
    __builtin_amdgcn_s_setprio(0);
  };

  stage(0);  // prefetch tile 0 into buf 0
#pragma unroll 1
  for (int s = 0; s < 7; ++s) {
    step(0, true);
    step(1, true);
  }
  step(0, true);   // tile 14, prefetch 15
  step(1, false);  // tile 15

  // ---- merge kv-halves (plain adds; no max was subtracted) ----
  __syncthreads();
  float* mb = (float*)&KV[0][0][0];  // 8192 floats, reuse K/V space
  if (wk == 1) {
#pragma unroll
    for (int qg = 0; qg < 2; ++qg) {
      smL[wq][qg][l] = lsum[qg];
#pragma unroll
      for (int dt = 0; dt < 2; ++dt)
#pragma unroll
        for (int r = 0; r < 16; ++r)
          mb[wq * 4096 + (qg * 32 + dt * 16 + r) * 64 + l] = accO[qg][dt][r];
    }
  }
  __syncthreads();
  if (wk == 0) {
#pragma unroll
    for (int qg = 0; qg < 2; ++qg) {
      lsum[qg] += smL[wq][qg][l];
#pragma unroll
      for (int dt = 0; dt < 2; ++dt)
#pragma unroll
        for (int r = 0; r < 16; ++r)
          accO[qg][dt][r] += mb[wq * 4096 + (qg * 32 + dt * 16 + r) * 64 + l];
      float inv = 1.0f / xhalf_sum(lsum[qg]);
      u16* ob = aoT + ((size_t)((b << 10) + q0 + qg * 32 + lq)) * C_ + h * 64;
#pragma unroll
      for (int dt = 0; dt < 2; ++dt)
#pragma unroll
        for (int rg = 0; rg < 4; ++rg) {
          int d0 = dt * 32 + rg * 8 + hi * 4;
          u32 w0 = cvtpk(accO[qg][dt][rg * 4 + 0] * inv, accO[qg][dt][rg * 4 + 1] * inv);
          u32 w1 = cvtpk(accO[qg][dt][rg * 4 + 2] * inv, accO[qg][dt][rg * 4 + 3] * inv);
          uint2 o = {w0, w1};
          *(uint2*)(ob + d0) = o;
        }
    }
  }
}

// ---- launcher ----
extern "C" void kernel_launch(void* const* d_in, const int* in_sizes, int n_in,
                              void* d_out, int out_size, void* d_ws, size_t ws_size,
                              hipStream_t stream) {
  const float* x = (const float*)d_in[0];
  const float* gamma = (const float*)d_in[1];
  const float* beta = (const float*)d_in[2];
  const float* qkv_w = (const float*)d_in[3];
  const float* qkv_b = (const float*)d_in[4];
  const float* proj_w = (const float*)d_in[5];
  const float* proj_b = (const float*)d_in[6];
  float* out = (float*)d_out;
  char* ws = (char*)d_ws;
  u16* wq = (u16*)(ws);                      // 1,572,864
  u16* wp = (u16*)(ws + 1572864);            //   524,288
  u16* ht = (u16*)(ws + 2097152);            // 16,777,216 (reused as aoT)
  u16* qkvo = (u16*)(ws + 18874368);         // 50,331,648 (only v band used)
  u16* qT = (u16*)(ws + 69206016);           // 16,777,216
  u16* kT = (u16*)(ws + 85983232);           // 16,777,216
  u16* aoT = ht;

  cast_bf16_kernel<<<3072, 256, 0, stream>>>(qkv_w, wq, M3_ * K_);
  cast_bf16_kernel<<<1024, 256, 0, stream>>>(proj_w, wp, C_ * K_);
  gnorm_kernel<<<512, 256, 0, stream>>>(x, gamma, beta, ht);
  gemm_kernel<0><<<dim3(128, 12), 256, 0, stream>>>(wq, ht, qkv_b, qkvo, qT, kT, nullptr, nullptr);
  attn_kernel<<<1024, 256, 0, stream>>>(qT, kT, qkvo, aoT);
  gemm_kernel<1><<<dim3(128, 4), 256, 0, stream>>>(wp, aoT, proj_b, nullptr, nullptr, nullptr, x, out);
}

// Round 6
// 131.328 us; speedup vs baseline: 2.8883x; 2.8883x over previous
//
#include <hip/hip_runtime.h>

typedef unsigned short u16;
typedef unsigned int u32;
typedef __bf16 bf16x8 __attribute__((ext_vector_type(8)));
typedef float f32x4 __attribute__((ext_vector_type(4)));
typedef float f32x16 __attribute__((ext_vector_type(16)));

#define B_ 16
#define C_ 512
#define N_ 1024
#define NB_ 16384   // B_*N_
#define K_ 512
#define M3_ 1536
#define SCALE_Q 0.18033688011112042f  // 0.125 * log2(e)

// ---- helpers ----
__device__ __forceinline__ u16 f2bf(float f) {
  u32 u = __float_as_uint(f);
  u32 r = (u + 0x7FFFu + ((u >> 16) & 1u)) >> 16;  // RNE
  return (u16)r;
}

__device__ __forceinline__ void gl_lds16(const void* g, void* l) {
  __builtin_amdgcn_global_load_lds(
      (const __attribute__((address_space(1))) u32*)(uintptr_t)g,
      (__attribute__((address_space(3))) u32*)(u32)(uintptr_t)l, 16, 0, 0);
}

__device__ __forceinline__ u32 cvtpk(float lo, float hi) {
  u32 r;
  asm("v_cvt_pk_bf16_f32 %0, %1, %2" : "=v"(r) : "v"(lo), "v"(hi));
  return r;
}

__device__ __forceinline__ float exp2a(float x) {
  float r;
  asm("v_exp_f32 %0, %1" : "=v"(r) : "v"(x));
  return r;
}

// (a,b) -> a' = {a_lo, b_lo}, b' = {a_hi, b_hi}
__device__ __forceinline__ void plswap2(u32& a, u32& b) {
#if __has_builtin(__builtin_amdgcn_permlane32_swap)
  auto r = __builtin_amdgcn_permlane32_swap((int)a, (int)b, false, false);
  a = (u32)r[0];
  b = (u32)r[1];
#else
  asm("v_permlane32_swap_b32 %0, %1" : "+v"(a), "+v"(b));
#endif
}

__device__ __forceinline__ float xhalf_sum(float x) {
  u32 a = __float_as_uint(x), b = a;
  plswap2(a, b);
  return __uint_as_float(a) + __uint_as_float(b);
}

// ---- kernel 1: fp32 -> bf16 cast for weights ----
__global__ __launch_bounds__(256) void cast_bf16_kernel(const float* __restrict__ src,
                                                        u16* __restrict__ dst, int n) {
  int i = blockIdx.x * 256 + threadIdx.x;
  if (i < n) dst[i] = f2bf(src[i]);
}

// ---- kernel 2: GroupNorm, writes h^T as (B*N, C) bf16 ----
__global__ __launch_bounds__(256) void gnorm_kernel(const float* __restrict__ x,
                                                    const float* __restrict__ gamma,
                                                    const float* __restrict__ beta,
                                                    u16* __restrict__ ht) {
  int blk = blockIdx.x;
  int b = blk >> 5, g = blk & 31;
  int t = threadIdx.x;
  const float* xb = x + ((size_t)(b * C_ + g * 16) << 10);
  float v[16][4];
  float s = 0.f, sq = 0.f;
#pragma unroll
  for (int cc = 0; cc < 16; ++cc) {
#pragma unroll
    for (int r = 0; r < 4; ++r) {
      float f = xb[cc * 1024 + r * 256 + t];
      v[cc][r] = f; s += f; sq += f * f;
    }
  }
#pragma unroll
  for (int m = 32; m >= 1; m >>= 1) { s += __shfl_xor(s, m, 64); sq += __shfl_xor(sq, m, 64); }
  __shared__ float red[8];
  int w = t >> 6;
  if ((t & 63) == 0) { red[w * 2] = s; red[w * 2 + 1] = sq; }
  __syncthreads();
  s = red[0] + red[2] + red[4] + red[6];
  sq = red[1] + red[3] + red[5] + red[7];
  float mean = s * (1.f / 16384.f);
  float var = sq * (1.f / 16384.f) - mean * mean;
  float rstd = rsqrtf(var + 1e-5f);
  float gm[16], bt[16];
#pragma unroll
  for (int cc = 0; cc < 16; ++cc) {
    gm[cc] = gamma[g * 16 + cc] * rstd;
    bt[cc] = beta[g * 16 + cc];
  }
  u16* hb = ht + ((size_t)(b << 10)) * C_ + g * 16;
#pragma unroll
  for (int r = 0; r < 4; ++r) {
    u32 pk[8];
#pragma unroll
    for (int q = 0; q < 8; ++q) {
      float f0 = (v[2 * q][r] - mean) * gm[2 * q] + bt[2 * q];
      float f1 = (v[2 * q + 1][r] - mean) * gm[2 * q + 1] + bt[2 * q + 1];
      pk[q] = (u32)f2bf(f0) | ((u32)f2bf(f1) << 16);
    }
    u16* dp = hb + (size_t)(r * 256 + t) * C_;
    uint4 a = {pk[0], pk[1], pk[2], pk[3]};
    uint4 b4 = {pk[4], pk[5], pk[6], pk[7]};
    *(uint4*)dp = a;
    *(uint4*)(dp + 8) = b4;
  }
}

// ---- GEMM: C[MxNB] = A[MxK] * BT[NBxK]^T ; 128x128 tile, BK=64, 4 waves ----
// EPI 0: qkv GEMM. q,k bands (rows<1024) are stored TRANSPOSED per-(b,h) as
//        (n, d) bf16 into qTo/kTo (q pre-scaled); v band stored (o, bn) in Co.
// EPI 1: out = x + val + bias -> fp32 (b,c,n)
template <int EPI>
__global__ __launch_bounds__(256) void gemm_kernel(const u16* __restrict__ A,
                                                   const u16* __restrict__ BT,
                                                   const float* __restrict__ bias,
                                                   u16* __restrict__ Co,
                                                   u16* __restrict__ qTo,
                                                   u16* __restrict__ kTo,
                                                   const float* __restrict__ xres,
                                                   float* __restrict__ Fo) {
  __shared__ u16 ldsA[128 * 64];
  __shared__ u16 ldsB[128 * 64];
  int t = threadIdx.x;
  int l = t & 63, w = t >> 6;
  int wr = w >> 1, wc = w & 1;
  int ro0 = blockIdx.y * 128, co0 = blockIdx.x * 128;
  f32x4 acc[4][4];
#pragma unroll
  for (int m = 0; m < 4; ++m)
#pragma unroll
    for (int n = 0; n < 4; ++n) acc[m][n] = {0.f, 0.f, 0.f, 0.f};
  int srow = t >> 3, sg = t & 7;
  for (int kt = 0; kt < 8; ++kt) {
    int k0 = kt * 64;
#pragma unroll
    for (int i = 0; i < 4; ++i) {
      int row = i * 32 + srow;
      int gl = sg ^ (row & 7);
      gl_lds16(A + (size_t)(ro0 + row) * K_ + k0 + gl * 8, ldsA + (i * 32 + w * 8) * 64);
      gl_lds16(BT + (size_t)(co0 + row) * K_ + k0 + gl * 8, ldsB + (i * 32 + w * 8) * 64);
    }
    __syncthreads();
#pragma unroll
    for (int ks = 0; ks < 2; ++ks) {
      bf16x8 af[4], bfr[4];
#pragma unroll
      for (int m = 0; m < 4; ++m) {
        int row = wr * 64 + m * 16 + (l & 15);
        int ph = (ks * 4 + (l >> 4)) ^ (row & 7);
        af[m] = *(const bf16x8*)&ldsA[row * 64 + ph * 8];
      }
#pragma unroll
      for (int n = 0; n < 4; ++n) {
        int row = wc * 64 + n * 16 + (l & 15);
        int ph = (ks * 4 + (l >> 4)) ^ (row & 7);
        bfr[n] = *(const bf16x8*)&ldsB[row * 64 + ph * 8];
      }
#pragma unroll
      for (int m = 0; m < 4; ++m)
#pragma unroll
        for (int n = 0; n < 4; ++n)
          acc[m][n] = __builtin_amdgcn_mfma_f32_16x16x32_bf16(af[m], bfr[n], acc[m][n], 0, 0, 0);
    }
    __syncthreads();
  }
  if (EPI == 0 && ro0 < 1024) {
    // q/k band: transposed store into (b,h)(n,d) layout
    int sel = ro0 >> 9;
    u16* dstb = sel ? kTo : qTo;
    float scl = sel ? 1.f : SCALE_Q;
#pragma unroll
    for (int m = 0; m < 4; ++m) {
      int row0 = ro0 + wr * 64 + m * 16 + (l >> 4) * 4;
      int o = row0 & 511;
      int h = o >> 6, d0 = o & 63;
      float bv0 = bias[row0], bv1 = bias[row0 + 1];
      float bv2 = bias[row0 + 2], bv3 = bias[row0 + 3];
#pragma unroll
      for (int n = 0; n < 4; ++n) {
        int col = co0 + wc * 64 + n * 16 + (l & 15);
        int bb = col >> 10, nn = col & 1023;
        float v0 = (acc[m][n][0] + bv0) * scl;
        float v1 = (acc[m][n][1] + bv1) * scl;
        float v2 = (acc[m][n][2] + bv2) * scl;
        float v3 = (acc[m][n][3] + bv3) * scl;
        uint2 ov = {cvtpk(v0, v1), cvtpk(v2, v3)};
        *(uint2*)(dstb + ((size_t)((bb * 8 + h) << 10) + nn) * 64 + d0) = ov;
      }
    }
  } else {
#pragma unroll
    for (int m = 0; m < 4; ++m) {
#pragma unroll
      for (int j = 0; j < 4; ++j) {
        int row = ro0 + wr * 64 + m * 16 + (l >> 4) * 4 + j;
        float bv = bias[row];
#pragma unroll
        for (int n = 0; n < 4; ++n) {
          int col = co0 + wc * 64 + n * 16 + (l & 15);
          float val = acc[m][n][j] + bv;
          if (EPI == 0) {
            Co[(size_t)row * NB_ + col] = f2bf(val);
          } else {
            int bb = col >> 10, nn = col & 1023;
            size_t oi = (((size_t)(bb * C_ + row)) << 10) + nn;
            Fo[oi] = xres[oi] + val;
          }
        }
      }
    }
  }
}

// ---- kernel 4: flash attention, 4 waves x 32 q-rows sharing one KV stream ----
// Per-wave state is small (~120 regs incl. accumulators) -> 4 waves/SIMD.
// KVBLK=32 double-buffered in 16KB LDS; staging split 2 global_load_lds/wave.
// Step discipline (validated r5): vmcnt(0) own loads -> s_barrier -> stage(next)
// -> read buf -> compute. Stage targets buf^1 (not read this step): race-free.
__global__ __launch_bounds__(256) void attn_kernel(const u16* __restrict__ qT,
                                                   const u16* __restrict__ kT,
                                                   const u16* __restrict__ qkv,
                                                   u16* __restrict__ aoT) {
  __shared__ u16 KV[2][4096];  // [buf][0..2047 = K(32kv x 64d) | 2048..4095 = V(64d x 32kv)]
  int bid = blockIdx.x;
  int wid = (bid & 7) * 128 + (bid >> 3);  // XCD swizzle: 8 blocks of a head on one XCD
  int qt2 = wid & 7, h = (wid >> 3) & 7, b = wid >> 6;
  int bh = b * 8 + h;
  int t = threadIdx.x, l = t & 63, w = t >> 6;
  int lq = l & 31, hi = l >> 5;
  int q0 = qt2 * 128 + w * 32;

  // Q fragments (scale pre-folded in qkv GEMM epilogue)
  const u16* qbase = qT + ((size_t)(bh << 10) + q0 + lq) * 64 + hi * 8;
  bf16x8 qf[4];
#pragma unroll
  for (int kc = 0; kc < 4; ++kc) qf[kc] = *(const bf16x8*)(qbase + kc * 16);

  f32x16 accO[2];
#pragma unroll
  for (int dt = 0; dt < 2; ++dt)
#pragma unroll
    for (int r = 0; r < 16; ++r) accO[dt][r] = 0.f;
  float lsum = 0.f;

  // staging: 8 gl_lds16 per tile, wave w issues 2.
  // waves 0,1 -> K instrs {2w, 2w+1}: rows i*8+(l>>3), granule (l&7)^(row&7)
  // waves 2,3 -> V instrs {2(w-2), 2(w-2)+1}: d-rows j*16+(l>>2), granule (l&3)^((row>>1)&3)
  const u16 *src0, *src1;
  u32 ldso0, ldso1;
  int adv;
  if (w < 2) {
    int i0 = 2 * w, i1 = 2 * w + 1;
    src0 = kT + ((size_t)(bh << 10) + i0 * 8 + (l >> 3)) * 64 + (((l & 7) ^ ((l >> 3) & 7)) * 8);
    src1 = kT + ((size_t)(bh << 10) + i1 * 8 + (l >> 3)) * 64 + (((l & 7) ^ ((l >> 3) & 7)) * 8);
    ldso0 = i0 * 512; ldso1 = i1 * 512;
    adv = 2048;  // 32 kv-rows * 64
  } else {
    int j0 = 2 * (w - 2), j1 = 2 * (w - 2) + 1;
    src0 = qkv + (size_t)(2 * C_ + h * 64 + j0 * 16 + (l >> 2)) * NB_ + (b << 10) +
           (((l & 3) ^ ((l >> 3) & 3)) * 8);
    src1 = qkv + (size_t)(2 * C_ + h * 64 + j1 * 16 + (l >> 2)) * NB_ + (b << 10) +
           (((l & 3) ^ ((l >> 3) & 3)) * 8);
    ldso0 = 2048 + j0 * 512; ldso1 = 2048 + j1 * 512;
    adv = 32;    // 32 kv-cols
  }

  // LDS read offsets (within buf 0; buf 1 = +4096 elems)
  const u16* kfp[4];
#pragma unroll
  for (int kc = 0; kc < 4; ++kc)
    kfp[kc] = &KV[0][0] + lq * 64 + (((2 * kc + hi) ^ (lq & 7)) * 8);
  const u16* vfp[4];
#pragma unroll
  for (int dt = 0; dt < 2; ++dt)
#pragma unroll
    for (int kcc = 0; kcc < 2; ++kcc)
      vfp[dt * 2 + kcc] = &KV[0][0] + 2048 + (dt * 32 + lq) * 32 +
                          (((kcc * 2 + hi) ^ ((lq >> 1) & 3)) * 8);

  auto stage = [&](int buf) {
    gl_lds16(src0, &KV[buf][0] + ldso0);
    gl_lds16(src1, &KV[buf][0] + ldso1);
    src0 += adv;
    src1 += adv;
  };

  auto step = [&](int buf, bool dostage) {
    asm volatile("s_waitcnt vmcnt(0)" ::: "memory");  // own 2 loads of tile s landed
    __builtin_amdgcn_sched_barrier(0);
    __builtin_amdgcn_s_barrier();                     // everyone's tile-s writes landed
    __builtin_amdgcn_sched_barrier(0);
    if (dostage) stage(buf ^ 1);                      // prefetch tile s+1 into other buf
    bf16x8 kf[4];
#pragma unroll
    for (int kc = 0; kc < 4; ++kc) kf[kc] = *(const bf16x8*)(kfp[kc] + buf * 4096);
    f32x16 sc;
#pragma unroll
    for (int r = 0; r < 16; ++r) sc[r] = 0.f;
    __builtin_amdgcn_s_setprio(1);
#pragma unroll
    for (int kc = 0; kc < 4; ++kc)
      sc = __builtin_amdgcn_mfma_f32_32x32x16_bf16(kf[kc], qf[kc], sc, 0, 0, 0);
    __builtin_amdgcn_s_setprio(0);
    bf16x8 vf[4];
#pragma unroll
    for (int j = 0; j < 4; ++j) vf[j] = *(const bf16x8*)(vfp[j] + buf * 4096);
    // P = exp2(S); log2-domain scores, constant shift cancels in O = PV / sum P
    float p0 = 0.f, p1 = 0.f, p2 = 0.f, p3 = 0.f;
#pragma unroll
    for (int r = 0; r < 4; ++r) {
      float e0 = exp2a(sc[4 * r + 0]);
      float e1 = exp2a(sc[4 * r + 1]);
      float e2 = exp2a(sc[4 * r + 2]);
      float e3 = exp2a(sc[4 * r + 3]);
      sc[4 * r + 0] = e0; sc[4 * r + 1] = e1;
      sc[4 * r + 2] = e2; sc[4 * r + 3] = e3;
      p0 += e0; p1 += e1; p2 += e2; p3 += e3;
    }
    lsum += (p0 + p1) + (p2 + p3);
    u32 pk[8];
#pragma unroll
    for (int p = 0; p < 8; ++p) pk[p] = cvtpk(sc[2 * p], sc[2 * p + 1]);
    u32 pfu[2][4];
#pragma unroll
    for (int cc = 0; cc < 2; ++cc) {
      u32 w0 = pk[cc * 4 + 0], w2 = pk[cc * 4 + 2];
      u32 w1 = pk[cc * 4 + 1], w3 = pk[cc * 4 + 3];
      plswap2(w0, w2);
      plswap2(w1, w3);
      pfu[cc][0] = w0; pfu[cc][1] = w1; pfu[cc][2] = w2; pfu[cc][3] = w3;
    }
    __builtin_amdgcn_s_setprio(1);
#pragma unroll
    for (int kcc = 0; kcc < 2; ++kcc)
#pragma unroll
      for (int dt = 0; dt < 2; ++dt) {
        union { u32 u[4]; bf16x8 v; } pf;
        pf.u[0] = pfu[kcc][0]; pf.u[1] = pfu[kcc][1];
        pf.u[2] = pfu[kcc][2]; pf.u[3] = pfu[kcc][3];
        accO[dt] = __builtin_amdgcn_mfma_f32_32x32x16_bf16(vf[dt * 2 + kcc], pf.v, accO[dt], 0, 0, 0);
      }
    __builtin_amdgcn_s_setprio(0);
  };

  stage(0);  // prefetch tile 0 into buf 0
#pragma unroll 1
  for (int s = 0; s < 15; ++s) {
    step(0, true);
    step(1, true);
  }
  step(0, true);   // tile 30, prefetch 31
  step(1, false);  // tile 31

  float inv = 1.0f / xhalf_sum(lsum);
  u16* ob = aoT + ((size_t)((b << 10) + q0 + lq)) * C_ + h * 64;
#pragma unroll
  for (int dt = 0; dt < 2; ++dt)
#pragma unroll
    for (int rg = 0; rg < 4; ++rg) {
      int d0 = dt * 32 + rg * 8 + hi * 4;
      u32 w0 = cvtpk(accO[dt][rg * 4 + 0] * inv, accO[dt][rg * 4 + 1] * inv);
      u32 w1 = cvtpk(accO[dt][rg * 4 + 2] * inv, accO[dt][rg * 4 + 3] * inv);
      uint2 o = {w0, w1};
      *(uint2*)(ob + d0) = o;
    }
}

// ---- launcher ----
extern "C" void kernel_launch(void* const* d_in, const int* in_sizes, int n_in,
                              void* d_out, int out_size, void* d_ws, size_t ws_size,
                              hipStream_t stream) {
  const float* x = (const float*)d_in[0];
  const float* gamma = (const float*)d_in[1];
  const float* beta = (const float*)d_in[2];
  const float* qkv_w = (const float*)d_in[3];
  const float* qkv_b = (const float*)d_in[4];
  const float* proj_w = (const float*)d_in[5];
  const float* proj_b = (const float*)d_in[6];
  float* out = (float*)d_out;
  char* ws = (char*)d_ws;
  u16* wq = (u16*)(ws);                      // 1,572,864
  u16* wp = (u16*)(ws + 1572864);            //   524,288
  u16* ht = (u16*)(ws + 2097152);            // 16,777,216 (reused as aoT)
  u16* qkvo = (u16*)(ws + 18874368);         // 50,331,648 (only v band used)
  u16* qT = (u16*)(ws + 69206016);           // 16,777,216
  u16* kT = (u16*)(ws + 85983232);           // 16,777,216
  u16* aoT = ht;

  cast_bf16_kernel<<<3072, 256, 0, stream>>>(qkv_w, wq, M3_ * K_);
  cast_bf16_kernel<<<1024, 256, 0, stream>>>(proj_w, wp, C_ * K_);
  gnorm_kernel<<<512, 256, 0, stream>>>(x, gamma, beta, ht);
  gemm_kernel<0><<<dim3(128, 12), 256, 0, stream>>>(wq, ht, qkv_b, qkvo, qT, kT, nullptr, nullptr);
  attn_kernel<<<1024, 256, 0, stream>>>(qT, kT, qkvo, aoT);
  gemm_kernel<1><<<dim3(128, 4), 256, 0, stream>>>(wp, aoT, proj_b, nullptr, nullptr, nullptr, x, out);
}